// Round 19
// baseline (144.167 us; speedup 1.0000x reference)
//
#include <hip/hip_runtime.h>
#include <stdint.h>

#define N_TOK 8192
#define C_DIM 768
#define E_NUM 8
#define NTK 24                // K-tiles of 32
#define GRIDG 624             // 8 xcd * 13 q * 6 y
#define PREP_WT 10368         // 18 mats * 24 * 24 tiles
#define PREP_TOT (PREP_WT + N_TOK / 4)

typedef short short8 __attribute__((ext_vector_type(8)));
typedef __bf16 bf16x8 __attribute__((ext_vector_type(8)));
typedef float f32x4 __attribute__((ext_vector_type(4)));

static __device__ __forceinline__ unsigned short f2bf(float f) {
    unsigned u = __float_as_uint(f);
    unsigned r = u + 0x7FFFu + ((u >> 16) & 1u);
    return (unsigned short)(r >> 16);
}
static __device__ __forceinline__ float bf2f(unsigned short h) {
    return __uint_as_float(((unsigned)h) << 16);
}

// ---- fused prep: blocks [0,10368) transpose+convert weights; [10368,..) router top-2 + xb ----
__global__ __launch_bounds__(256) void prep_kernel(const float* __restrict__ wfc,
                                                   const float* __restrict__ wpj,
                                                   const float* __restrict__ w1,
                                                   const float* __restrict__ w2,
                                                   unsigned short* __restrict__ Wt,
                                                   const float* __restrict__ x,
                                                   const float* __restrict__ rw,
                                                   const float* __restrict__ bias,
                                                   float* __restrict__ topk_w,
                                                   int* __restrict__ eids,
                                                   unsigned short* __restrict__ xb) {
    __shared__ float tile[32][33];
    const int bx = blockIdx.x;
    const int t = threadIdx.x;
    if (bx < PREP_WT) {
        const int m = bx / 576;
        const int rem = bx - m * 576;
        const int i0 = (rem / 24) * 32;
        const int o0 = (rem % 24) * 32;
        const int tx = t & 31, ty = t >> 5;   // 32 x 8
        const float* src = (m == 0) ? wfc : (m == 1) ? wpj
                         : (m < 10) ? (w1 + (size_t)(m - 2) * C_DIM * C_DIM)
                                    : (w2 + (size_t)(m - 10) * C_DIM * C_DIM);
        #pragma unroll
        for (int rr = 0; rr < 32; rr += 8)
            tile[ty + rr][tx] = src[(size_t)(i0 + ty + rr) * C_DIM + o0 + tx];
        __syncthreads();
        unsigned short* dst = Wt + (size_t)m * C_DIM * C_DIM;
        #pragma unroll
        for (int rr = 0; rr < 32; rr += 8) {
            int o = o0 + ty + rr;
            dst[(size_t)o * C_DIM + i0 + tx] = f2bf(tile[tx][ty + rr]);
        }
    } else {
        const int rb = bx - PREP_WT;
        const int wave = t >> 6;
        const int lane = t & 63;
        const int n = rb * 4 + wave;
        const float* xp = x + (size_t)n * C_DIM + lane * 12;
        float xv[12];
        #pragma unroll
        for (int j = 0; j < 12; j++) xv[j] = xp[j];
        unsigned short* xbp = xb + (size_t)n * C_DIM + lane * 12;
        #pragma unroll
        for (int j = 0; j < 12; j++) xbp[j] = f2bf(xv[j]);
        float acc[E_NUM];
        #pragma unroll
        for (int e = 0; e < E_NUM; e++) acc[e] = 0.f;
        #pragma unroll
        for (int e = 0; e < E_NUM; e++) {
            const float* wp = rw + (size_t)e * C_DIM + lane * 12;
            #pragma unroll
            for (int j = 0; j < 12; j++) acc[e] += xv[j] * wp[j];
        }
        #pragma unroll
        for (int e = 0; e < E_NUM; e++) {
            #pragma unroll
            for (int off = 32; off > 0; off >>= 1) acc[e] += __shfl_xor(acc[e], off, 64);
        }
        if (lane == 0) {
            float sc[E_NUM];
            #pragma unroll
            for (int e = 0; e < E_NUM; e++) sc[e] = 1.f / (1.f + expf(-acc[e]));
            int e0 = 0; float best = -1e30f;
            #pragma unroll
            for (int e = 0; e < E_NUM; e++) { float v = sc[e] + bias[e]; if (v > best) { best = v; e0 = e; } }
            int e1 = -1; float best1 = -1e30f;
            #pragma unroll
            for (int e = 0; e < E_NUM; e++) { if (e == e0) continue; float v = sc[e] + bias[e]; if (v > best1) { best1 = v; e1 = e; } }
            float w0 = sc[e0], w1 = sc[e1];
            float s = w0 + w1 + 1e-20f;
            w0 /= s; w1 /= s;
            topk_w[n * 2] = w0; topk_w[n * 2 + 1] = w1;
            eids[n * 2] = e0; eids[n * 2 + 1] = e1;
        }
    }
}

// ---------------- router pass 2: per-expert compaction (deterministic) ----------------
__global__ __launch_bounds__(1024) void bucketize_kernel(const int* __restrict__ eids,
                                                         int* __restrict__ counts,
                                                         int* __restrict__ buckets) {
    const int e = blockIdx.x;
    const int t = threadIdx.x;
    const int wv = t >> 6, lane = t & 63;
    __shared__ int wave_tot[16];
    int running = 0;
    for (int start = 0; start < 2 * N_TOK; start += 1024) {
        const int i = start + t;
        const int f = (eids[i] == e) ? 1 : 0;
        unsigned long long mask = __ballot(f);
        int pre = __popcll(mask & ((1ull << lane) - 1ull));
        if (lane == 0) wave_tot[wv] = __popcll(mask);
        __syncthreads();
        int wbase = 0, tot = 0;
        #pragma unroll
        for (int j = 0; j < 16; j++) { int c = wave_tot[j]; tot += c; if (j < wv) wbase += c; }
        if (f) buckets[e * N_TOK + running + wbase + pre] = i;
        running += tot;
        __syncthreads();
    }
    if (t == 0) counts[e] = running;
}

// ---- merged bf16 MFMA GEMM: 256x128 tile, 4 waves of 128x64, BK=32, 3-buf ring ----
// r18 post-mortem: per-CU LDS READ pipe is the binding resource (149 ds_read_b128/CU-step with
// 64x64 wave tiles = 0.5 reads/MFMA). 128x64 wave tiles cut that to 0.375 reads/MFMA (12 reads,
// 32 MFMA per wave-step) at identical staging traffic -> 96 reads/CU-step, 35% less LDS load.
// 4 waves (256 thr), acc 8x4 = 128 VGPR (r9 precedent: 124), A-frag read inside i-loop.
// PHASE 0 (fc):   A = xb (shared direct; expert gather token=bk[pos]>>1);
//                 epi relu^2 -> Hsh[n] (shared) / H[xx*256+local] compacted (expert)
// PHASE 1 (proj): A = Hsh (shared) / H[xx*256+row] dense;
//                 epi -> out[n] fp32 (shared) / Y[ent] bf16 (expert; combine sums)
// Grid decode (r12): xx = xcd*13 + i6/6 (XCD-contiguous), y = i6%6 innermost.
// 3-buf ring, 72 KiB (2 blocks/CU), counted WAITVM(6); single barrier per step.
// Bank swizzle (HW-verified r3): 16B slot' = slot ^ ((row>>1)&3); rows = q*64 + (t>>2) so
// (row>>1)&3 == (t>>3)&3 for every chunk q.
#define GLOAD_LDS(g, l) __builtin_amdgcn_global_load_lds((const __attribute__((address_space(1))) void*)(g), (__attribute__((address_space(3))) void*)(l), 16, 0, 0)
#define WAITVM(n) asm volatile("s_waitcnt vmcnt(" #n ")" ::: "memory")
#define SCHEDB() __builtin_amdgcn_sched_barrier(0)
#define BAR() __builtin_amdgcn_s_barrier()

template <int PHASE>
__global__ __launch_bounds__(256, 2) void gemm_all_kernel(const unsigned short* __restrict__ Adir,
                                                          const unsigned short* __restrict__ Agat,
                                                          const unsigned short* __restrict__ WtAll,
                                                          void* __restrict__ dstDir,
                                                          unsigned short* __restrict__ dstGat,
                                                          const int* __restrict__ counts,
                                                          const int* __restrict__ buckets) {
    const int fid = blockIdx.x;
    const int xcd = fid & 7;
    const int i6 = fid >> 3;              // 0..77
    const int xx = xcd * 13 + i6 / 6;     // XCD-contiguous xx (champion decode, r12)
    const int y = i6 % 6;
    // per-block prefix from counts (256-row units)
    int cz[E_NUM];
    #pragma unroll
    for (int zz = 0; zz < E_NUM; zz++) cz[zz] = counts[zz];
    int xo[E_NUM + 1]; int a = 0;
    #pragma unroll
    for (int zz = 0; zz < E_NUM; zz++) { xo[zz] = a; a += (cz[zz] + 255) >> 8; }
    xo[E_NUM] = a;
    if (xx >= a + 32) return;
    const bool sh = (xx >= a);
    int z = 0, xl = xx - a;
    if (!sh) {
        #pragma unroll
        for (int zz = 0; zz < E_NUM; zz++)
            if (xx >= xo[zz] && xx < xo[zz + 1]) { z = zz; xl = xx - xo[zz]; }
    }
    const int rows = sh ? N_TOK : cz[z];
    const int r0 = xl * 256;
    const int c0 = y * 128;

    __shared__ __align__(16) unsigned short lds[3 * 12288];   // 72 KiB, 3-buffer ring

    const int t = threadIdx.x;
    const int lane = t & 63;
    const int wv = t >> 6;                // 0..3
    const int wm = wv >> 1;               // 0..1 -> 128-row half
    const int wn = wv & 1;                // 0..1 -> 64-col band

    const int widx = sh ? (PHASE == 0 ? 0 : 1) : (PHASE == 0 ? 2 + z : 10 + z);
    const unsigned short* Bmat = WtAll + (size_t)widx * C_DIM * C_DIM;
    const int* bk = buckets + z * N_TOK;

    // staging: 6 instrs/thread/tile. Instr covers 64 rows: row = q*64 + (t>>2), 16B slot t&3.
    // A: q=0..3 (rows 0..255); B: q=0..1 (rows 0..127). Source col pre-swizzled:
    // (t&3) ^ ((row>>1)&3) == (t&3) ^ ((t>>3)&3).
    const int srow = t >> 2;              // 0..63
    const int scol = (((t & 3) ^ ((t >> 3) & 3)) * 8);
    int gA[4];
    const unsigned short* Asrc;
    if (sh) {
        Asrc = Adir;
        #pragma unroll
        for (int q = 0; q < 4; q++) gA[q] = r0 + q * 64 + srow;
    } else if (PHASE == 0) {
        Asrc = Agat;  // xb gathered by token
        #pragma unroll
        for (int q = 0; q < 4; q++) {
            int p = r0 + q * 64 + srow;
            gA[q] = bk[p < rows ? p : rows - 1] >> 1;
        }
    } else {
        Asrc = Agat;  // H compacted: dense rows
        #pragma unroll
        for (int q = 0; q < 4; q++) gA[q] = xx * 256 + q * 64 + srow;
    }
    const unsigned short* ap[4];
    const unsigned short* bp[2];
    #pragma unroll
    for (int q = 0; q < 4; q++) ap[q] = Asrc + (size_t)gA[q] * C_DIM + scol;
    #pragma unroll
    for (int q = 0; q < 2; q++) bp[q] = Bmat + (size_t)(c0 + q * 64 + srow) * C_DIM + scol;

    f32x4 acc[8][4];
    #pragma unroll
    for (int i = 0; i < 8; i++)
        #pragma unroll
        for (int j = 0; j < 4; j++) acc[i][j] = (f32x4){0.f, 0.f, 0.f, 0.f};

    // fragment-read swizzled k-slot: slot = fq ^ ((fr>>1)&3)
    const int fr = lane & 15;
    const int fq = lane >> 4;
    const int ks = ((fq ^ ((fr >> 1) & 3)) * 8);

    // prologue: stage tiles 0,1 into buffers 0,1 (12 vm-ops per thread outstanding)
    #pragma unroll
    for (int p = 0; p < 2; ++p) {
        unsigned short* d = lds + p * 12288 + t * 8;
        const int ko = p * 32;
        #pragma unroll
        for (int q = 0; q < 4; q++) GLOAD_LDS(ap[q] + ko, d + q * 2048);
        #pragma unroll
        for (int q = 0; q < 2; q++) GLOAD_LDS(bp[q] + ko, d + 8192 + q * 2048);
    }

    #pragma unroll
    for (int kt = 0; kt < NTK; ++kt) {
        if (kt + 1 < NTK) { WAITVM(6); }   // tile kt landed; kt+1's 6 (and kt+2's) in flight
        else              { WAITVM(0); }
        BAR();          // tile kt visible; all waves done reading buf[(kt+2)%3]'s old tile
        SCHEDB();
        if (kt + 2 < NTK) {
            unsigned short* d = lds + ((kt + 2) % 3) * 12288 + t * 8;
            const int ko = (kt + 2) * 32;
            #pragma unroll
            for (int q = 0; q < 4; q++) GLOAD_LDS(ap[q] + ko, d + q * 2048);
            #pragma unroll
            for (int q = 0; q < 2; q++) GLOAD_LDS(bp[q] + ko, d + 8192 + q * 2048);
        }
        SCHEDB();       // stage issued before compute; compute may not hoist above
        const unsigned short* buf = lds + (kt % 3) * 12288;
        short8 bfr[4];
        #pragma unroll
        for (int j = 0; j < 4; j++)
            bfr[j] = *reinterpret_cast<const short8*>(buf + 8192 + (size_t)(wn * 64 + j * 16 + fr) * 32 + ks);
        __builtin_amdgcn_s_setprio(1);
        #pragma unroll
        for (int i = 0; i < 8; i++) {
            short8 afr = *reinterpret_cast<const short8*>(buf + (size_t)(wm * 128 + i * 16 + fr) * 32 + ks);
            #pragma unroll
            for (int j = 0; j < 4; j++)
                acc[i][j] = __builtin_amdgcn_mfma_f32_16x16x32_bf16(
                    __builtin_bit_cast(bf16x8, afr), __builtin_bit_cast(bf16x8, bfr[j]), acc[i][j], 0, 0, 0);
        }
        __builtin_amdgcn_s_setprio(0);
        // single barrier per step: stage(kt+2) targets buf[(kt-1)%3], whose readers all
        // passed this step's BAR before the overwrite begins.
    }

    // ---- epilogue: rows (local) wm*128 + i*16 + fq*4 + rr; cols c0 + wn*64 + j*16 + fr ----
    const int orow = wm * 128;
    const int ocol = c0 + wn * 64;
    if constexpr (PHASE == 0) {
        #pragma unroll
        for (int i = 0; i < 8; i++)
            #pragma unroll
            for (int rr = 0; rr < 4; rr++) {
                int local = orow + i * 16 + fq * 4 + rr;
                #pragma unroll
                for (int j = 0; j < 4; j++) {
                    float v = acc[i][j][rr];
                    float rl = v > 0.f ? v : 0.f;
                    unsigned short hv = f2bf(rl * rl);
                    if (sh) {
                        ((unsigned short*)dstDir)[(size_t)(r0 + local) * C_DIM + ocol + j * 16 + fr] = hv;
                    } else if (r0 + local < rows) {
                        dstGat[(size_t)(xx * 256 + local) * C_DIM + ocol + j * 16 + fr] = hv;  // compacted
                    }
                }
            }
    } else {
        #pragma unroll
        for (int i = 0; i < 8; i++)
            #pragma unroll
            for (int rr = 0; rr < 4; rr++) {
                int local = orow + i * 16 + fq * 4 + rr;
                int pos = r0 + local;
                if (sh) {
                    float* od = (float*)dstDir;
                    size_t base = (size_t)pos * C_DIM;
                    #pragma unroll
                    for (int j = 0; j < 4; j++)
                        od[base + ocol + j * 16 + fr] = acc[i][j][rr];
                } else if (pos < rows) {
                    int ent = bk[pos];
                    size_t base = (size_t)ent * C_DIM;
                    #pragma unroll
                    for (int j = 0; j < 4; j++)
                        dstGat[base + ocol + j * 16 + fr] = f2bf(acc[i][j][rr]);
                }
            }
    }
}

// ---------------- combine: out += w0*Y[n,0] + w1*Y[n,1] ----------------
__global__ void combine_kernel(float* __restrict__ out, const unsigned short* __restrict__ Y,
                               const float* __restrict__ tw) {
    int idx = blockIdx.x * blockDim.x + threadIdx.x;
    const int per_row = C_DIM / 4;
    if (idx >= N_TOK * per_row) return;
    int n = idx / per_row;
    int c = (idx % per_row) * 4;
    float w0 = tw[n * 2], w1 = tw[n * 2 + 1];
    const ushort4 a = *reinterpret_cast<const ushort4*>(Y + (size_t)(n * 2) * C_DIM + c);
    const ushort4 b = *reinterpret_cast<const ushort4*>(Y + (size_t)(n * 2 + 1) * C_DIM + c);
    float4* op = reinterpret_cast<float4*>(out + (size_t)n * C_DIM + c);
    float4 o = *op;
    o.x += w0 * bf2f(a.x) + w1 * bf2f(b.x);
    o.y += w0 * bf2f(a.y) + w1 * bf2f(b.y);
    o.z += w0 * bf2f(a.z) + w1 * bf2f(b.z);
    o.w += w0 * bf2f(a.w) + w1 * bf2f(b.w);
    *op = o;
}

extern "C" void kernel_launch(void* const* d_in, const int* in_sizes, int n_in,
                              void* d_out, int out_size, void* d_ws, size_t ws_size,
                              hipStream_t stream) {
    const float* x   = (const float*)d_in[0];
    const float* wfc = (const float*)d_in[1];
    const float* wpj = (const float*)d_in[2];
    const float* w1  = (const float*)d_in[3];
    const float* w2  = (const float*)d_in[4];
    const float* rw  = (const float*)d_in[5];
    const float* bias= (const float*)d_in[6];
    float* out = (float*)d_out;

    char* ws = (char*)d_ws;
    size_t off = 0;
    auto alloc = [&](size_t bytes) { void* p = ws + off; off += (bytes + 255) & ~(size_t)255; return p; };
    unsigned short* xb   = (unsigned short*)alloc((size_t)N_TOK * C_DIM * 2);
    unsigned short* Wt   = (unsigned short*)alloc((size_t)18 * C_DIM * C_DIM * 2);
    unsigned short* H    = (unsigned short*)alloc((size_t)104 * 256 * C_DIM * 2); // compacted expert hidden
    unsigned short* Hsh  = (unsigned short*)alloc((size_t)N_TOK * C_DIM * 2);     // shared hidden
    unsigned short* Y    = (unsigned short*)alloc((size_t)N_TOK * 2 * C_DIM * 2); // expert out, by entry
    float* topk_w        = (float*)alloc((size_t)N_TOK * 2 * 4);
    int* counts          = (int*)alloc(256);
    int* buckets         = (int*)alloc((size_t)E_NUM * N_TOK * 4);
    int* eids            = (int*)alloc((size_t)2 * N_TOK * 4);

    prep_kernel<<<PREP_TOT, 256, 0, stream>>>(wfc, wpj, w1, w2, Wt, x, rw, bias, topk_w, eids, xb);
    bucketize_kernel<<<E_NUM, 1024, 0, stream>>>(eids, counts, buckets);

    gemm_all_kernel<0><<<GRIDG, 256, 0, stream>>>(xb, xb, Wt, Hsh, H, counts, buckets);
    gemm_all_kernel<1><<<GRIDG, 256, 0, stream>>>(Hsh, H, Wt, out, Y, counts, buckets);

    combine_kernel<<<(N_TOK * (C_DIM / 4) + 255) / 256, 256, 0, stream>>>(out, Y, topk_w);
}

// Round 20
// 130.437 us; speedup vs baseline: 1.1053x; 1.1053x over previous
//
#include <hip/hip_runtime.h>
#include <stdint.h>

#define N_TOK 8192
#define C_DIM 768
#define E_NUM 8
#define NTK 24                // K-tiles of 32
#define GRIDG 624             // 8 xcd * 13 q * 6 y
#define AUX_WT 10368          // 18 mats * 24 * 24 tiles
#define AUX_TOT (8 + AUX_WT)  // 8 bucketize blocks + wtrans blocks

typedef short short8 __attribute__((ext_vector_type(8)));
typedef __bf16 bf16x8 __attribute__((ext_vector_type(8)));
typedef float f32x4 __attribute__((ext_vector_type(4)));

static __device__ __forceinline__ unsigned short f2bf(float f) {
    unsigned u = __float_as_uint(f);
    unsigned r = u + 0x7FFFu + ((u >> 16) & 1u);
    return (unsigned short)(r >> 16);
}
static __device__ __forceinline__ float bf2f(unsigned short h) {
    return __uint_as_float(((unsigned)h) << 16);
}

// ---------------- router: fp32 logits, sigmoid, top-2 (no atomics); emits xb = bf16(x) ----------
__global__ __launch_bounds__(256) void router_kernel(const float* __restrict__ x,
                                                     const float* __restrict__ rw,
                                                     const float* __restrict__ bias,
                                                     float* __restrict__ topk_w,
                                                     int* __restrict__ eids,
                                                     unsigned short* __restrict__ xb) {
    const int wave = threadIdx.x >> 6;
    const int lane = threadIdx.x & 63;
    const int n = blockIdx.x * 4 + wave;
    const float* xp = x + (size_t)n * C_DIM + lane * 12;
    float xv[12];
    #pragma unroll
    for (int j = 0; j < 12; j++) xv[j] = xp[j];
    unsigned short* xbp = xb + (size_t)n * C_DIM + lane * 12;
    #pragma unroll
    for (int j = 0; j < 12; j++) xbp[j] = f2bf(xv[j]);
    float acc[E_NUM];
    #pragma unroll
    for (int e = 0; e < E_NUM; e++) acc[e] = 0.f;
    #pragma unroll
    for (int e = 0; e < E_NUM; e++) {
        const float* wp = rw + (size_t)e * C_DIM + lane * 12;
        #pragma unroll
        for (int j = 0; j < 12; j++) acc[e] += xv[j] * wp[j];
    }
    #pragma unroll
    for (int e = 0; e < E_NUM; e++) {
        #pragma unroll
        for (int off = 32; off > 0; off >>= 1) acc[e] += __shfl_xor(acc[e], off, 64);
    }
    if (lane == 0) {
        float sc[E_NUM];
        #pragma unroll
        for (int e = 0; e < E_NUM; e++) sc[e] = 1.f / (1.f + expf(-acc[e]));
        int e0 = 0; float best = -1e30f;
        #pragma unroll
        for (int e = 0; e < E_NUM; e++) { float v = sc[e] + bias[e]; if (v > best) { best = v; e0 = e; } }
        int e1 = -1; float best1 = -1e30f;
        #pragma unroll
        for (int e = 0; e < E_NUM; e++) { if (e == e0) continue; float v = sc[e] + bias[e]; if (v > best1) { best1 = v; e1 = e; } }
        float w0 = sc[e0], w1 = sc[e1];
        float s = w0 + w1 + 1e-20f;
        w0 /= s; w1 /= s;
        topk_w[n * 2] = w0; topk_w[n * 2 + 1] = w1;
        eids[n * 2] = e0; eids[n * 2 + 1] = e1;
    }
}

// ---- fused aux: blocks 0..7 = per-expert bucketize (hidden under wtrans); 8.. = wtrans ----
__global__ __launch_bounds__(1024) void aux_kernel(const float* __restrict__ wfc,
                                                   const float* __restrict__ wpj,
                                                   const float* __restrict__ w1,
                                                   const float* __restrict__ w2,
                                                   unsigned short* __restrict__ Wt,
                                                   const int* __restrict__ eids,
                                                   int* __restrict__ counts,
                                                   int* __restrict__ buckets) {
    const int bx = blockIdx.x;
    const int t = threadIdx.x;
    if (bx < 8) {
        // ---- bucketize expert e = bx (deterministic ballot-scan compaction) ----
        const int e = bx;
        const int wv = t >> 6, lane = t & 63;
        __shared__ int wave_tot[16];
        int running = 0;
        for (int start = 0; start < 2 * N_TOK; start += 1024) {
            const int i = start + t;
            const int f = (eids[i] == e) ? 1 : 0;
            unsigned long long mask = __ballot(f);
            int pre = __popcll(mask & ((1ull << lane) - 1ull));
            if (lane == 0) wave_tot[wv] = __popcll(mask);
            __syncthreads();
            int wbase = 0, tot = 0;
            #pragma unroll
            for (int j = 0; j < 16; j++) { int c = wave_tot[j]; tot += c; if (j < wv) wbase += c; }
            if (f) buckets[e * N_TOK + running + wbase + pre] = i;
            running += tot;
            __syncthreads();
        }
        if (t == 0) counts[e] = running;
    } else {
        // ---- transpose+convert one 32x32 weight tile: Wt[m][o][i] = W[m][i][o], bf16 ----
        __shared__ float tile[32][33];
        const int wb = bx - 8;
        const int m = wb / 576;
        const int rem = wb - m * 576;
        const int i0 = (rem / 24) * 32;
        const int o0 = (rem % 24) * 32;
        const int tx = t & 31, ty = t >> 5;   // 32 x 32, 1 elem/thread
        const float* src = (m == 0) ? wfc : (m == 1) ? wpj
                         : (m < 10) ? (w1 + (size_t)(m - 2) * C_DIM * C_DIM)
                                    : (w2 + (size_t)(m - 10) * C_DIM * C_DIM);
        tile[ty][tx] = src[(size_t)(i0 + ty) * C_DIM + o0 + tx];
        __syncthreads();
        unsigned short* dst = Wt + (size_t)m * C_DIM * C_DIM;
        dst[(size_t)(o0 + ty) * C_DIM + i0 + tx] = f2bf(tile[tx][ty]);
    }
}

// ---- merged bf16 MFMA GEMM: 256x128 tile, 8 waves, BK=32, 3-buf ring, counted vmcnt ----
// (r12 champion, byte-identical.)
// PHASE 0 (fc):   A = xb (shared direct; expert gather token=ent>>1); epi relu^2 -> Hsh[n] / H[ent]
// PHASE 1 (proj): A = Hsh (shared) / H gathered by ent (expert);      epi -> out[n] fp32 / Y[ent]
// Grid decode: xx = xcd*13 + i6/6 (XCD-contiguous, FETCH ~33 MB), y = i6%6 innermost.
// 3-buf ring, 72 KiB, counted WAITVM(3) never drains till tail; single barrier per step.
// Bank swizzle (HW-verified r3): 16B slot' = slot ^ ((row>>1)&3).
#define GLOAD_LDS(g, l) __builtin_amdgcn_global_load_lds((const __attribute__((address_space(1))) void*)(g), (__attribute__((address_space(3))) void*)(l), 16, 0, 0)
#define WAITVM(n) asm volatile("s_waitcnt vmcnt(" #n ")" ::: "memory")
#define SCHEDB() __builtin_amdgcn_sched_barrier(0)
#define BAR() __builtin_amdgcn_s_barrier()

template <int PHASE>
__global__ __launch_bounds__(512, 4) void gemm_all_kernel(const unsigned short* __restrict__ Adir,
                                                          const unsigned short* __restrict__ Agat,
                                                          const unsigned short* __restrict__ WtAll,
                                                          void* __restrict__ dstDir,
                                                          unsigned short* __restrict__ dstGat,
                                                          const int* __restrict__ counts,
                                                          const int* __restrict__ buckets) {
    const int fid = blockIdx.x;
    const int xcd = fid & 7;
    const int i6 = fid >> 3;              // 0..77
    const int xx = xcd * 13 + i6 / 6;     // XCD-contiguous xx (champion decode)
    const int y = i6 % 6;
    // per-block prefix from counts (256-row units)
    int cz[E_NUM];
    #pragma unroll
    for (int zz = 0; zz < E_NUM; zz++) cz[zz] = counts[zz];
    int xo[E_NUM + 1]; int a = 0;
    #pragma unroll
    for (int zz = 0; zz < E_NUM; zz++) { xo[zz] = a; a += (cz[zz] + 255) >> 8; }
    xo[E_NUM] = a;
    if (xx >= a + 32) return;
    const bool sh = (xx >= a);
    int z = 0, xl = xx - a;
    if (!sh) {
        #pragma unroll
        for (int zz = 0; zz < E_NUM; zz++)
            if (xx >= xo[zz] && xx < xo[zz + 1]) { z = zz; xl = xx - xo[zz]; }
    }
    const int rows = sh ? N_TOK : cz[z];
    const int r0 = xl * 256;
    const int c0 = y * 128;

    __shared__ __align__(16) unsigned short lds[3 * 12288];   // 72 KiB, 3-buffer ring

    const int t = threadIdx.x;
    const int lane = t & 63;
    const int wv = t >> 6;
    const int wm = wv >> 1;               // 0..3 -> 64-row band
    const int wn = wv & 1;                // 0..1 -> 64-col band

    const int widx = sh ? (PHASE == 0 ? 0 : 1) : (PHASE == 0 ? 2 + z : 10 + z);
    const unsigned short* Bmat = WtAll + (size_t)widx * C_DIM * C_DIM;
    const int* bk = buckets + z * N_TOK;

    // staging geometry: A instr j (j=0,1): rows j*128 + wv*16 + (lane>>2); B: rows wv*16+(lane>>2)
    // global source col pre-swizzled: (lane&3) ^ ((lane>>3)&3)
    const int scol = (((lane & 3) ^ ((lane >> 3) & 3)) * 8);
    const int rA0 = wv * 16 + (lane >> 2);
    const int rA1 = 128 + rA0;
    int g0, g1;
    const unsigned short* Asrc;
    if (sh) {
        Asrc = Adir;
        g0 = r0 + rA0; g1 = r0 + rA1;
    } else {
        Asrc = Agat;
        int p0 = r0 + rA0, p1 = r0 + rA1;
        int e0v = bk[p0 < rows ? p0 : rows - 1];
        int e1v = bk[p1 < rows ? p1 : rows - 1];
        g0 = (PHASE == 0) ? (e0v >> 1) : e0v;
        g1 = (PHASE == 0) ? (e1v >> 1) : e1v;
    }
    const unsigned short* ap0 = Asrc + (size_t)g0 * C_DIM + scol;
    const unsigned short* ap1 = Asrc + (size_t)g1 * C_DIM + scol;
    const unsigned short* bp  = Bmat + (size_t)(c0 + rA0) * C_DIM + scol;

    f32x4 acc[4][4];
    #pragma unroll
    for (int i = 0; i < 4; i++)
        #pragma unroll
        for (int j = 0; j < 4; j++) acc[i][j] = (f32x4){0.f, 0.f, 0.f, 0.f};

    // fragment-read swizzled k-slot: slot = fq ^ ((fr>>1)&3)
    const int fr = lane & 15;
    const int fq = lane >> 4;
    const int ks = ((fq ^ ((fr >> 1) & 3)) * 8);

    // prologue: stage tiles 0,1 into buffers 0,1 (6 vm-ops per thread outstanding)
    #pragma unroll
    for (int p = 0; p < 2; ++p) {
        unsigned short* d = lds + p * 12288;
        const int ko = p * 32;
        GLOAD_LDS(ap0 + ko, d + wv * 512 + lane * 8);
        GLOAD_LDS(ap1 + ko, d + 4096 + wv * 512 + lane * 8);
        GLOAD_LDS(bp + ko,  d + 8192 + wv * 512 + lane * 8);
    }

    #pragma unroll
    for (int kt = 0; kt < NTK; ++kt) {
        if (kt + 1 < NTK) { WAITVM(3); }   // tile kt landed; tiles kt+1/kt+2 stay in flight
        else              { WAITVM(0); }
        BAR();          // tile kt visible; all waves done reading buf[(kt+2)%3]'s old tile
        SCHEDB();
        if (kt + 2 < NTK) {
            unsigned short* d = lds + ((kt + 2) % 3) * 12288;
            const int ko = (kt + 2) * 32;
            GLOAD_LDS(ap0 + ko, d + wv * 512 + lane * 8);
            GLOAD_LDS(ap1 + ko, d + 4096 + wv * 512 + lane * 8);
            GLOAD_LDS(bp + ko,  d + 8192 + wv * 512 + lane * 8);
        }
        SCHEDB();       // stage issued before compute; compute may not hoist above
        const unsigned short* buf = lds + (kt % 3) * 12288;
        short8 afr[4], bfr[4];
        #pragma unroll
        for (int i = 0; i < 4; i++)
            afr[i] = *reinterpret_cast<const short8*>(buf + (size_t)(wm * 64 + i * 16 + fr) * 32 + ks);
        #pragma unroll
        for (int j = 0; j < 4; j++)
            bfr[j] = *reinterpret_cast<const short8*>(buf + 8192 + (size_t)(wn * 64 + j * 16 + fr) * 32 + ks);
        __builtin_amdgcn_s_setprio(1);
        #pragma unroll
        for (int i = 0; i < 4; i++)
            #pragma unroll
            for (int j = 0; j < 4; j++)
                acc[i][j] = __builtin_amdgcn_mfma_f32_16x16x32_bf16(
                    __builtin_bit_cast(bf16x8, afr[i]), __builtin_bit_cast(bf16x8, bfr[j]), acc[i][j], 0, 0, 0);
        __builtin_amdgcn_s_setprio(0);
        // single barrier per step: stage(kt+2) targets buf[(kt-1)%3], whose readers all
        // passed this step's BAR before the overwrite begins.
    }

    // ---- epilogue: rows r0 + wm*64 + i*16 + fq*4 + rr; cols c0 + wn*64 + j*16 + fr ----
    const int orow = r0 + wm * 64;
    const int ocol = c0 + wn * 64;
    if (sh) {
        if constexpr (PHASE == 0) {
            unsigned short* Hd = (unsigned short*)dstDir;
            #pragma unroll
            for (int i = 0; i < 4; i++)
                #pragma unroll
                for (int rr = 0; rr < 4; rr++) {
                    size_t base = (size_t)(orow + i * 16 + fq * 4 + rr) * C_DIM;
                    #pragma unroll
                    for (int j = 0; j < 4; j++) {
                        float v = acc[i][j][rr];
                        float rl = v > 0.f ? v : 0.f;
                        Hd[base + ocol + j * 16 + fr] = f2bf(rl * rl);
                    }
                }
        } else {
            float* od = (float*)dstDir;
            #pragma unroll
            for (int i = 0; i < 4; i++)
                #pragma unroll
                for (int rr = 0; rr < 4; rr++) {
                    size_t base = (size_t)(orow + i * 16 + fq * 4 + rr) * C_DIM;
                    #pragma unroll
                    for (int j = 0; j < 4; j++)
                        od[base + ocol + j * 16 + fr] = acc[i][j][rr];
                }
        }
    } else {
        #pragma unroll
        for (int i = 0; i < 4; i++)
            #pragma unroll
            for (int rr = 0; rr < 4; rr++) {
                int pos = orow + i * 16 + fq * 4 + rr;
                if (pos < rows) {
                    int ent = bk[pos];
                    size_t base = (size_t)ent * C_DIM;
                    #pragma unroll
                    for (int j = 0; j < 4; j++) {
                        float v = acc[i][j][rr];
                        if (PHASE == 0) {
                            float rl = v > 0.f ? v : 0.f;
                            dstGat[base + ocol + j * 16 + fr] = f2bf(rl * rl);
                        } else {
                            dstGat[base + ocol + j * 16 + fr] = f2bf(v);
                        }
                    }
                }
            }
    }
}

// ---------------- combine: out += w0*Y[n,0] + w1*Y[n,1] ----------------
__global__ void combine_kernel(float* __restrict__ out, const unsigned short* __restrict__ Y,
                               const float* __restrict__ tw) {
    int idx = blockIdx.x * blockDim.x + threadIdx.x;
    const int per_row = C_DIM / 4;
    if (idx >= N_TOK * per_row) return;
    int n = idx / per_row;
    int c = (idx % per_row) * 4;
    float w0 = tw[n * 2], w1 = tw[n * 2 + 1];
    const ushort4 a = *reinterpret_cast<const ushort4*>(Y + (size_t)(n * 2) * C_DIM + c);
    const ushort4 b = *reinterpret_cast<const ushort4*>(Y + (size_t)(n * 2 + 1) * C_DIM + c);
    float4* op = reinterpret_cast<float4*>(out + (size_t)n * C_DIM + c);
    float4 o = *op;
    o.x += w0 * bf2f(a.x) + w1 * bf2f(b.x);
    o.y += w0 * bf2f(a.y) + w1 * bf2f(b.y);
    o.z += w0 * bf2f(a.z) + w1 * bf2f(b.z);
    o.w += w0 * bf2f(a.w) + w1 * bf2f(b.w);
    *op = o;
}

extern "C" void kernel_launch(void* const* d_in, const int* in_sizes, int n_in,
                              void* d_out, int out_size, void* d_ws, size_t ws_size,
                              hipStream_t stream) {
    const float* x   = (const float*)d_in[0];
    const float* wfc = (const float*)d_in[1];
    const float* wpj = (const float*)d_in[2];
    const float* w1  = (const float*)d_in[3];
    const float* w2  = (const float*)d_in[4];
    const float* rw  = (const float*)d_in[5];
    const float* bias= (const float*)d_in[6];
    float* out = (float*)d_out;

    char* ws = (char*)d_ws;
    size_t off = 0;
    auto alloc = [&](size_t bytes) { void* p = ws + off; off += (bytes + 255) & ~(size_t)255; return p; };
    unsigned short* xb   = (unsigned short*)alloc((size_t)N_TOK * C_DIM * 2);
    unsigned short* Wt   = (unsigned short*)alloc((size_t)18 * C_DIM * C_DIM * 2);
    unsigned short* H    = (unsigned short*)alloc((size_t)N_TOK * 2 * C_DIM * 2);  // expert hidden, by entry
    unsigned short* Hsh  = (unsigned short*)alloc((size_t)N_TOK * C_DIM * 2);      // shared hidden
    unsigned short* Y    = (unsigned short*)alloc((size_t)N_TOK * 2 * C_DIM * 2);  // expert out, by entry
    float* topk_w        = (float*)alloc((size_t)N_TOK * 2 * 4);
    int* counts          = (int*)alloc(256);
    int* buckets         = (int*)alloc((size_t)E_NUM * N_TOK * 4);
    int* eids            = (int*)alloc((size_t)2 * N_TOK * 4);

    router_kernel<<<N_TOK / 4, 256, 0, stream>>>(x, rw, bias, topk_w, eids, xb);
    aux_kernel<<<AUX_TOT, 1024, 0, stream>>>(wfc, wpj, w1, w2, Wt, eids, counts, buckets);

    gemm_all_kernel<0><<<GRIDG, 512, 0, stream>>>(xb, xb, Wt, Hsh, H, counts, buckets);
    gemm_all_kernel<1><<<GRIDG, 512, 0, stream>>>(Hsh, H, Wt, out, Y, counts, buckets);

    combine_kernel<<<(N_TOK * (C_DIM / 4) + 255) / 256, 256, 0, stream>>>(out, Y, topk_w);
}

// Round 21
// 128.887 us; speedup vs baseline: 1.1186x; 1.0120x over previous
//
#include <hip/hip_runtime.h>
#include <stdint.h>

#define N_TOK 8192
#define C_DIM 768
#define E_NUM 8
#define NTK 24                // K-tiles of 32
#define GRIDG 624             // 8 xcd * 13 q * 6 y
#define PREP_RT 2048          // router blocks (4 tokens each)
#define PREP_WT 10368         // 18 mats * 24 * 24 tiles
#define PREP_TOT (PREP_RT + PREP_WT)

typedef short short8 __attribute__((ext_vector_type(8)));
typedef __bf16 bf16x8 __attribute__((ext_vector_type(8)));
typedef float f32x4 __attribute__((ext_vector_type(4)));

static __device__ __forceinline__ unsigned short f2bf(float f) {
    unsigned u = __float_as_uint(f);
    unsigned r = u + 0x7FFFu + ((u >> 16) & 1u);
    return (unsigned short)(r >> 16);
}
static __device__ __forceinline__ float bf2f(unsigned short h) {
    return __uint_as_float(((unsigned)h) << 16);
}

// ---- fused prep: blocks [0,2048) router top-2 + xb; [2048,..) transpose+convert weights ----
// (router first so routing results are ready earliest; wtrans has no dependency on router)
__global__ __launch_bounds__(256) void prep_kernel(const float* __restrict__ wfc,
                                                   const float* __restrict__ wpj,
                                                   const float* __restrict__ w1,
                                                   const float* __restrict__ w2,
                                                   unsigned short* __restrict__ Wt,
                                                   const float* __restrict__ x,
                                                   const float* __restrict__ rw,
                                                   const float* __restrict__ bias,
                                                   float* __restrict__ topk_w,
                                                   int* __restrict__ eids,
                                                   unsigned short* __restrict__ xb) {
    const int bx = blockIdx.x;
    const int t = threadIdx.x;
    if (bx < PREP_RT) {
        const int wave = t >> 6;
        const int lane = t & 63;
        const int n = bx * 4 + wave;
        const float* xp = x + (size_t)n * C_DIM + lane * 12;
        float xv[12];
        #pragma unroll
        for (int j = 0; j < 12; j++) xv[j] = xp[j];
        unsigned short* xbp = xb + (size_t)n * C_DIM + lane * 12;
        #pragma unroll
        for (int j = 0; j < 12; j++) xbp[j] = f2bf(xv[j]);
        float acc[E_NUM];
        #pragma unroll
        for (int e = 0; e < E_NUM; e++) acc[e] = 0.f;
        #pragma unroll
        for (int e = 0; e < E_NUM; e++) {
            const float* wp = rw + (size_t)e * C_DIM + lane * 12;
            #pragma unroll
            for (int j = 0; j < 12; j++) acc[e] += xv[j] * wp[j];
        }
        #pragma unroll
        for (int e = 0; e < E_NUM; e++) {
            #pragma unroll
            for (int off = 32; off > 0; off >>= 1) acc[e] += __shfl_xor(acc[e], off, 64);
        }
        if (lane == 0) {
            float sc[E_NUM];
            #pragma unroll
            for (int e = 0; e < E_NUM; e++) sc[e] = 1.f / (1.f + expf(-acc[e]));
            int e0 = 0; float best = -1e30f;
            #pragma unroll
            for (int e = 0; e < E_NUM; e++) { float v = sc[e] + bias[e]; if (v > best) { best = v; e0 = e; } }
            int e1 = -1; float best1 = -1e30f;
            #pragma unroll
            for (int e = 0; e < E_NUM; e++) { if (e == e0) continue; float v = sc[e] + bias[e]; if (v > best1) { best1 = v; e1 = e; } }
            float w0 = sc[e0], w1 = sc[e1];
            float s = w0 + w1 + 1e-20f;
            w0 /= s; w1 /= s;
            topk_w[n * 2] = w0; topk_w[n * 2 + 1] = w1;
            eids[n * 2] = e0; eids[n * 2 + 1] = e1;
        }
    } else {
        __shared__ float tile[32][33];
        const int wb = bx - PREP_RT;
        const int m = wb / 576;
        const int rem = wb - m * 576;
        const int i0 = (rem / 24) * 32;
        const int o0 = (rem % 24) * 32;
        const int tx = t & 31, ty = t >> 5;   // 32 x 8
        const float* src = (m == 0) ? wfc : (m == 1) ? wpj
                         : (m < 10) ? (w1 + (size_t)(m - 2) * C_DIM * C_DIM)
                                    : (w2 + (size_t)(m - 10) * C_DIM * C_DIM);
        #pragma unroll
        for (int rr = 0; rr < 32; rr += 8)
            tile[ty + rr][tx] = src[(size_t)(i0 + ty + rr) * C_DIM + o0 + tx];
        __syncthreads();
        unsigned short* dst = Wt + (size_t)m * C_DIM * C_DIM;
        #pragma unroll
        for (int rr = 0; rr < 32; rr += 8) {
            int o = o0 + ty + rr;
            dst[(size_t)o * C_DIM + i0 + tx] = f2bf(tile[tx][ty + rr]);
        }
    }
}

// ---------------- router pass 2: per-expert compaction (deterministic, 8 blocks) ----------------
__global__ __launch_bounds__(1024) void bucketize_kernel(const int* __restrict__ eids,
                                                         int* __restrict__ counts,
                                                         int* __restrict__ buckets) {
    const int e = blockIdx.x;
    const int t = threadIdx.x;
    const int wv = t >> 6, lane = t & 63;
    __shared__ int wave_tot[16];
    int running = 0;
    for (int start = 0; start < 2 * N_TOK; start += 1024) {
        const int i = start + t;
        const int f = (eids[i] == e) ? 1 : 0;
        unsigned long long mask = __ballot(f);
        int pre = __popcll(mask & ((1ull << lane) - 1ull));
        if (lane == 0) wave_tot[wv] = __popcll(mask);
        __syncthreads();
        int wbase = 0, tot = 0;
        #pragma unroll
        for (int j = 0; j < 16; j++) { int c = wave_tot[j]; tot += c; if (j < wv) wbase += c; }
        if (f) buckets[e * N_TOK + running + wbase + pre] = i;
        running += tot;
        __syncthreads();
    }
    if (t == 0) counts[e] = running;
}

// ---- merged bf16 MFMA GEMM: 256x128 tile, 8 waves, BK=32, 3-buf ring, counted vmcnt ----
// (champion, byte-identical to r20.)
// PHASE 0 (fc):   A = xb (shared direct; expert gather token=ent>>1); epi relu^2 -> Hsh[n] / H[ent]
// PHASE 1 (proj): A = Hsh (shared) / H gathered by ent (expert);      epi -> out[n] fp32 / Y[ent]
// Grid decode: xx = xcd*13 + i6/6 (XCD-contiguous, FETCH ~33 MB), y = i6%6 innermost.
// 3-buf ring, 72 KiB, counted WAITVM(3) never drains till tail; single barrier per step.
// Bank swizzle (HW-verified r3): 16B slot' = slot ^ ((row>>1)&3).
#define GLOAD_LDS(g, l) __builtin_amdgcn_global_load_lds((const __attribute__((address_space(1))) void*)(g), (__attribute__((address_space(3))) void*)(l), 16, 0, 0)
#define WAITVM(n) asm volatile("s_waitcnt vmcnt(" #n ")" ::: "memory")
#define SCHEDB() __builtin_amdgcn_sched_barrier(0)
#define BAR() __builtin_amdgcn_s_barrier()

template <int PHASE>
__global__ __launch_bounds__(512, 4) void gemm_all_kernel(const unsigned short* __restrict__ Adir,
                                                          const unsigned short* __restrict__ Agat,
                                                          const unsigned short* __restrict__ WtAll,
                                                          void* __restrict__ dstDir,
                                                          unsigned short* __restrict__ dstGat,
                                                          const int* __restrict__ counts,
                                                          const int* __restrict__ buckets) {
    const int fid = blockIdx.x;
    const int xcd = fid & 7;
    const int i6 = fid >> 3;              // 0..77
    const int xx = xcd * 13 + i6 / 6;     // XCD-contiguous xx (champion decode)
    const int y = i6 % 6;
    // per-block prefix from counts (256-row units)
    int cz[E_NUM];
    #pragma unroll
    for (int zz = 0; zz < E_NUM; zz++) cz[zz] = counts[zz];
    int xo[E_NUM + 1]; int a = 0;
    #pragma unroll
    for (int zz = 0; zz < E_NUM; zz++) { xo[zz] = a; a += (cz[zz] + 255) >> 8; }
    xo[E_NUM] = a;
    if (xx >= a + 32) return;
    const bool sh = (xx >= a);
    int z = 0, xl = xx - a;
    if (!sh) {
        #pragma unroll
        for (int zz = 0; zz < E_NUM; zz++)
            if (xx >= xo[zz] && xx < xo[zz + 1]) { z = zz; xl = xx - xo[zz]; }
    }
    const int rows = sh ? N_TOK : cz[z];
    const int r0 = xl * 256;
    const int c0 = y * 128;

    __shared__ __align__(16) unsigned short lds[3 * 12288];   // 72 KiB, 3-buffer ring

    const int t = threadIdx.x;
    const int lane = t & 63;
    const int wv = t >> 6;
    const int wm = wv >> 1;               // 0..3 -> 64-row band
    const int wn = wv & 1;                // 0..1 -> 64-col band

    const int widx = sh ? (PHASE == 0 ? 0 : 1) : (PHASE == 0 ? 2 + z : 10 + z);
    const unsigned short* Bmat = WtAll + (size_t)widx * C_DIM * C_DIM;
    const int* bk = buckets + z * N_TOK;

    // staging geometry: A instr j (j=0,1): rows j*128 + wv*16 + (lane>>2); B: rows wv*16+(lane>>2)
    // global source col pre-swizzled: (lane&3) ^ ((lane>>3)&3)
    const int scol = (((lane & 3) ^ ((lane >> 3) & 3)) * 8);
    const int rA0 = wv * 16 + (lane >> 2);
    const int rA1 = 128 + rA0;
    int g0, g1;
    const unsigned short* Asrc;
    if (sh) {
        Asrc = Adir;
        g0 = r0 + rA0; g1 = r0 + rA1;
    } else {
        Asrc = Agat;
        int p0 = r0 + rA0, p1 = r0 + rA1;
        int e0v = bk[p0 < rows ? p0 : rows - 1];
        int e1v = bk[p1 < rows ? p1 : rows - 1];
        g0 = (PHASE == 0) ? (e0v >> 1) : e0v;
        g1 = (PHASE == 0) ? (e1v >> 1) : e1v;
    }
    const unsigned short* ap0 = Asrc + (size_t)g0 * C_DIM + scol;
    const unsigned short* ap1 = Asrc + (size_t)g1 * C_DIM + scol;
    const unsigned short* bp  = Bmat + (size_t)(c0 + rA0) * C_DIM + scol;

    f32x4 acc[4][4];
    #pragma unroll
    for (int i = 0; i < 4; i++)
        #pragma unroll
        for (int j = 0; j < 4; j++) acc[i][j] = (f32x4){0.f, 0.f, 0.f, 0.f};

    // fragment-read swizzled k-slot: slot = fq ^ ((fr>>1)&3)
    const int fr = lane & 15;
    const int fq = lane >> 4;
    const int ks = ((fq ^ ((fr >> 1) & 3)) * 8);

    // prologue: stage tiles 0,1 into buffers 0,1 (6 vm-ops per thread outstanding)
    #pragma unroll
    for (int p = 0; p < 2; ++p) {
        unsigned short* d = lds + p * 12288;
        const int ko = p * 32;
        GLOAD_LDS(ap0 + ko, d + wv * 512 + lane * 8);
        GLOAD_LDS(ap1 + ko, d + 4096 + wv * 512 + lane * 8);
        GLOAD_LDS(bp + ko,  d + 8192 + wv * 512 + lane * 8);
    }

    #pragma unroll
    for (int kt = 0; kt < NTK; ++kt) {
        if (kt + 1 < NTK) { WAITVM(3); }   // tile kt landed; tiles kt+1/kt+2 stay in flight
        else              { WAITVM(0); }
        BAR();          // tile kt visible; all waves done reading buf[(kt+2)%3]'s old tile
        SCHEDB();
        if (kt + 2 < NTK) {
            unsigned short* d = lds + ((kt + 2) % 3) * 12288;
            const int ko = (kt + 2) * 32;
            GLOAD_LDS(ap0 + ko, d + wv * 512 + lane * 8);
            GLOAD_LDS(ap1 + ko, d + 4096 + wv * 512 + lane * 8);
            GLOAD_LDS(bp + ko,  d + 8192 + wv * 512 + lane * 8);
        }
        SCHEDB();       // stage issued before compute; compute may not hoist above
        const unsigned short* buf = lds + (kt % 3) * 12288;
        short8 afr[4], bfr[4];
        #pragma unroll
        for (int i = 0; i < 4; i++)
            afr[i] = *reinterpret_cast<const short8*>(buf + (size_t)(wm * 64 + i * 16 + fr) * 32 + ks);
        #pragma unroll
        for (int j = 0; j < 4; j++)
            bfr[j] = *reinterpret_cast<const short8*>(buf + 8192 + (size_t)(wn * 64 + j * 16 + fr) * 32 + ks);
        __builtin_amdgcn_s_setprio(1);
        #pragma unroll
        for (int i = 0; i < 4; i++)
            #pragma unroll
            for (int j = 0; j < 4; j++)
                acc[i][j] = __builtin_amdgcn_mfma_f32_16x16x32_bf16(
                    __builtin_bit_cast(bf16x8, afr[i]), __builtin_bit_cast(bf16x8, bfr[j]), acc[i][j], 0, 0, 0);
        __builtin_amdgcn_s_setprio(0);
        // single barrier per step: stage(kt+2) targets buf[(kt-1)%3], whose readers all
        // passed this step's BAR before the overwrite begins.
    }

    // ---- epilogue: rows r0 + wm*64 + i*16 + fq*4 + rr; cols c0 + wn*64 + j*16 + fr ----
    const int orow = r0 + wm * 64;
    const int ocol = c0 + wn * 64;
    if (sh) {
        if constexpr (PHASE == 0) {
            unsigned short* Hd = (unsigned short*)dstDir;
            #pragma unroll
            for (int i = 0; i < 4; i++)
                #pragma unroll
                for (int rr = 0; rr < 4; rr++) {
                    size_t base = (size_t)(orow + i * 16 + fq * 4 + rr) * C_DIM;
                    #pragma unroll
                    for (int j = 0; j < 4; j++) {
                        float v = acc[i][j][rr];
                        float rl = v > 0.f ? v : 0.f;
                        Hd[base + ocol + j * 16 + fr] = f2bf(rl * rl);
                    }
                }
        } else {
            float* od = (float*)dstDir;
            #pragma unroll
            for (int i = 0; i < 4; i++)
                #pragma unroll
                for (int rr = 0; rr < 4; rr++) {
                    size_t base = (size_t)(orow + i * 16 + fq * 4 + rr) * C_DIM;
                    #pragma unroll
                    for (int j = 0; j < 4; j++)
                        od[base + ocol + j * 16 + fr] = acc[i][j][rr];
                }
        }
    } else {
        #pragma unroll
        for (int i = 0; i < 4; i++)
            #pragma unroll
            for (int rr = 0; rr < 4; rr++) {
                int pos = orow + i * 16 + fq * 4 + rr;
                if (pos < rows) {
                    int ent = bk[pos];
                    size_t base = (size_t)ent * C_DIM;
                    #pragma unroll
                    for (int j = 0; j < 4; j++) {
                        float v = acc[i][j][rr];
                        if (PHASE == 0) {
                            float rl = v > 0.f ? v : 0.f;
                            dstGat[base + ocol + j * 16 + fr] = f2bf(rl * rl);
                        } else {
                            dstGat[base + ocol + j * 16 + fr] = f2bf(v);
                        }
                    }
                }
            }
    }
}

// ---------------- combine: out += w0*Y[n,0] + w1*Y[n,1] (grid-stride, 512 thr) ----------------
__global__ __launch_bounds__(512) void combine_kernel(float* __restrict__ out,
                                                      const unsigned short* __restrict__ Y,
                                                      const float* __restrict__ tw) {
    const int per_row = C_DIM / 4;
    const int total = N_TOK * per_row;
    for (int idx = blockIdx.x * blockDim.x + threadIdx.x; idx < total; idx += gridDim.x * blockDim.x) {
        int n = idx / per_row;
        int c = (idx % per_row) * 4;
        float w0 = tw[n * 2], w1 = tw[n * 2 + 1];
        const ushort4 a = *reinterpret_cast<const ushort4*>(Y + (size_t)(n * 2) * C_DIM + c);
        const ushort4 b = *reinterpret_cast<const ushort4*>(Y + (size_t)(n * 2 + 1) * C_DIM + c);
        float4* op = reinterpret_cast<float4*>(out + (size_t)n * C_DIM + c);
        float4 o = *op;
        o.x += w0 * bf2f(a.x) + w1 * bf2f(b.x);
        o.y += w0 * bf2f(a.y) + w1 * bf2f(b.y);
        o.z += w0 * bf2f(a.z) + w1 * bf2f(b.z);
        o.w += w0 * bf2f(a.w) + w1 * bf2f(b.w);
        *op = o;
    }
}

extern "C" void kernel_launch(void* const* d_in, const int* in_sizes, int n_in,
                              void* d_out, int out_size, void* d_ws, size_t ws_size,
                              hipStream_t stream) {
    const float* x   = (const float*)d_in[0];
    const float* wfc = (const float*)d_in[1];
    const float* wpj = (const float*)d_in[2];
    const float* w1  = (const float*)d_in[3];
    const float* w2  = (const float*)d_in[4];
    const float* rw  = (const float*)d_in[5];
    const float* bias= (const float*)d_in[6];
    float* out = (float*)d_out;

    char* ws = (char*)d_ws;
    size_t off = 0;
    auto alloc = [&](size_t bytes) { void* p = ws + off; off += (bytes + 255) & ~(size_t)255; return p; };
    unsigned short* xb   = (unsigned short*)alloc((size_t)N_TOK * C_DIM * 2);
    unsigned short* Wt   = (unsigned short*)alloc((size_t)18 * C_DIM * C_DIM * 2);
    unsigned short* H    = (unsigned short*)alloc((size_t)N_TOK * 2 * C_DIM * 2);  // expert hidden, by entry
    unsigned short* Hsh  = (unsigned short*)alloc((size_t)N_TOK * C_DIM * 2);      // shared hidden
    unsigned short* Y    = (unsigned short*)alloc((size_t)N_TOK * 2 * C_DIM * 2);  // expert out, by entry
    float* topk_w        = (float*)alloc((size_t)N_TOK * 2 * 4);
    int* counts          = (int*)alloc(256);
    int* buckets         = (int*)alloc((size_t)E_NUM * N_TOK * 4);
    int* eids            = (int*)alloc((size_t)2 * N_TOK * 4);

    prep_kernel<<<PREP_TOT, 256, 0, stream>>>(wfc, wpj, w1, w2, Wt, x, rw, bias, topk_w, eids, xb);
    bucketize_kernel<<<E_NUM, 1024, 0, stream>>>(eids, counts, buckets);

    gemm_all_kernel<0><<<GRIDG, 512, 0, stream>>>(xb, xb, Wt, Hsh, H, counts, buckets);
    gemm_all_kernel<1><<<GRIDG, 512, 0, stream>>>(Hsh, H, Wt, out, Y, counts, buckets);

    combine_kernel<<<2048, 512, 0, stream>>>(out, Y, topk_w);
}

// Round 22
// 126.999 us; speedup vs baseline: 1.1352x; 1.0149x over previous
//
#include <hip/hip_runtime.h>
#include <stdint.h>

#define N_TOK 8192
#define C_DIM 768
#define E_NUM 8
#define NTK 24                // K-tiles of 32
#define GRIDG 624             // 8 xcd * 13 q * 6 y
#define PREP_RT 2048          // router blocks (4 tokens each)
#define PREP_WT 10368         // 18 mats * 24 * 24 tiles
#define PREP_TOT (PREP_RT + PREP_WT)

typedef short short8 __attribute__((ext_vector_type(8)));
typedef __bf16 bf16x8 __attribute__((ext_vector_type(8)));
typedef float f32x4 __attribute__((ext_vector_type(4)));

static __device__ __forceinline__ unsigned short f2bf(float f) {
    unsigned u = __float_as_uint(f);
    unsigned r = u + 0x7FFFu + ((u >> 16) & 1u);
    return (unsigned short)(r >> 16);
}
static __device__ __forceinline__ float bf2f(unsigned short h) {
    return __uint_as_float(((unsigned)h) << 16);
}

// ---- fused prep: blocks [0,2048) router top-2 + xb; [2048,..) transpose+convert weights ----
__global__ __launch_bounds__(256) void prep_kernel(const float* __restrict__ wfc,
                                                   const float* __restrict__ wpj,
                                                   const float* __restrict__ w1,
                                                   const float* __restrict__ w2,
                                                   unsigned short* __restrict__ Wt,
                                                   const float* __restrict__ x,
                                                   const float* __restrict__ rw,
                                                   const float* __restrict__ bias,
                                                   float* __restrict__ topk_w,
                                                   int* __restrict__ eids,
                                                   unsigned short* __restrict__ xb) {
    const int bx = blockIdx.x;
    const int t = threadIdx.x;
    if (bx < PREP_RT) {
        const int wave = t >> 6;
        const int lane = t & 63;
        const int n = bx * 4 + wave;
        const float* xp = x + (size_t)n * C_DIM + lane * 12;
        float xv[12];
        #pragma unroll
        for (int j = 0; j < 12; j++) xv[j] = xp[j];
        unsigned short* xbp = xb + (size_t)n * C_DIM + lane * 12;
        #pragma unroll
        for (int j = 0; j < 12; j++) xbp[j] = f2bf(xv[j]);
        float acc[E_NUM];
        #pragma unroll
        for (int e = 0; e < E_NUM; e++) acc[e] = 0.f;
        #pragma unroll
        for (int e = 0; e < E_NUM; e++) {
            const float* wp = rw + (size_t)e * C_DIM + lane * 12;
            #pragma unroll
            for (int j = 0; j < 12; j++) acc[e] += xv[j] * wp[j];
        }
        #pragma unroll
        for (int e = 0; e < E_NUM; e++) {
            #pragma unroll
            for (int off = 32; off > 0; off >>= 1) acc[e] += __shfl_xor(acc[e], off, 64);
        }
        if (lane == 0) {
            float sc[E_NUM];
            #pragma unroll
            for (int e = 0; e < E_NUM; e++) sc[e] = 1.f / (1.f + expf(-acc[e]));
            int e0 = 0; float best = -1e30f;
            #pragma unroll
            for (int e = 0; e < E_NUM; e++) { float v = sc[e] + bias[e]; if (v > best) { best = v; e0 = e; } }
            int e1 = -1; float best1 = -1e30f;
            #pragma unroll
            for (int e = 0; e < E_NUM; e++) { if (e == e0) continue; float v = sc[e] + bias[e]; if (v > best1) { best1 = v; e1 = e; } }
            float w0 = sc[e0], w1 = sc[e1];
            float s = w0 + w1 + 1e-20f;
            w0 /= s; w1 /= s;
            topk_w[n * 2] = w0; topk_w[n * 2 + 1] = w1;
            eids[n * 2] = e0; eids[n * 2 + 1] = e1;
        }
    } else {
        __shared__ float tile[32][33];
        const int wb = bx - PREP_RT;
        const int m = wb / 576;
        const int rem = wb - m * 576;
        const int i0 = (rem / 24) * 32;
        const int o0 = (rem % 24) * 32;
        const int tx = t & 31, ty = t >> 5;   // 32 x 8
        const float* src = (m == 0) ? wfc : (m == 1) ? wpj
                         : (m < 10) ? (w1 + (size_t)(m - 2) * C_DIM * C_DIM)
                                    : (w2 + (size_t)(m - 10) * C_DIM * C_DIM);
        #pragma unroll
        for (int rr = 0; rr < 32; rr += 8)
            tile[ty + rr][tx] = src[(size_t)(i0 + ty + rr) * C_DIM + o0 + tx];
        __syncthreads();
        unsigned short* dst = Wt + (size_t)m * C_DIM * C_DIM;
        #pragma unroll
        for (int rr = 0; rr < 32; rr += 8) {
            int o = o0 + ty + rr;
            dst[(size_t)o * C_DIM + i0 + tx] = f2bf(tile[tx][ty + rr]);
        }
    }
}

// ---------------- router pass 2: per-expert compaction (deterministic, 8 blocks) ----------------
__global__ __launch_bounds__(1024) void bucketize_kernel(const int* __restrict__ eids,
                                                         int* __restrict__ counts,
                                                         int* __restrict__ buckets) {
    const int e = blockIdx.x;
    const int t = threadIdx.x;
    const int wv = t >> 6, lane = t & 63;
    __shared__ int wave_tot[16];
    int running = 0;
    for (int start = 0; start < 2 * N_TOK; start += 1024) {
        const int i = start + t;
        const int f = (eids[i] == e) ? 1 : 0;
        unsigned long long mask = __ballot(f);
        int pre = __popcll(mask & ((1ull << lane) - 1ull));
        if (lane == 0) wave_tot[wv] = __popcll(mask);
        __syncthreads();
        int wbase = 0, tot = 0;
        #pragma unroll
        for (int j = 0; j < 16; j++) { int c = wave_tot[j]; tot += c; if (j < wv) wbase += c; }
        if (f) buckets[e * N_TOK + running + wbase + pre] = i;
        running += tot;
        __syncthreads();
    }
    if (t == 0) counts[e] = running;
}

// ---- merged bf16 MFMA GEMM: 256x128 tile, 8 waves, BK=32, 3-buf ring, counted vmcnt ----
// (champion K-loop, byte-identical to r21.)
// PHASE 0 (fc):   A = xb (shared direct; expert gather token=ent>>1); epi relu^2 -> Hsh[n] / H[ent]
// PHASE 1 (proj): A = Hsh (shared) / H gathered by ent (expert);
//                 epi -> S[n] bf16 (shared) / Y[ent] bf16 (expert); combine writes out w/o RMW.
// Grid decode: xx = xcd*13 + i6/6 (XCD-contiguous, FETCH ~33 MB), y = i6%6 innermost.
// 3-buf ring, 72 KiB, counted WAITVM(3) never drains till tail; single barrier per step.
// Bank swizzle (HW-verified r3): 16B slot' = slot ^ ((row>>1)&3).
#define GLOAD_LDS(g, l) __builtin_amdgcn_global_load_lds((const __attribute__((address_space(1))) void*)(g), (__attribute__((address_space(3))) void*)(l), 16, 0, 0)
#define WAITVM(n) asm volatile("s_waitcnt vmcnt(" #n ")" ::: "memory")
#define SCHEDB() __builtin_amdgcn_sched_barrier(0)
#define BAR() __builtin_amdgcn_s_barrier()

template <int PHASE>
__global__ __launch_bounds__(512, 4) void gemm_all_kernel(const unsigned short* __restrict__ Adir,
                                                          const unsigned short* __restrict__ Agat,
                                                          const unsigned short* __restrict__ WtAll,
                                                          unsigned short* __restrict__ dstDir,
                                                          unsigned short* __restrict__ dstGat,
                                                          const int* __restrict__ counts,
                                                          const int* __restrict__ buckets) {
    const int fid = blockIdx.x;
    const int xcd = fid & 7;
    const int i6 = fid >> 3;              // 0..77
    const int xx = xcd * 13 + i6 / 6;     // XCD-contiguous xx (champion decode)
    const int y = i6 % 6;
    // per-block prefix from counts (256-row units)
    int cz[E_NUM];
    #pragma unroll
    for (int zz = 0; zz < E_NUM; zz++) cz[zz] = counts[zz];
    int xo[E_NUM + 1]; int a = 0;
    #pragma unroll
    for (int zz = 0; zz < E_NUM; zz++) { xo[zz] = a; a += (cz[zz] + 255) >> 8; }
    xo[E_NUM] = a;
    if (xx >= a + 32) return;
    const bool sh = (xx >= a);
    int z = 0, xl = xx - a;
    if (!sh) {
        #pragma unroll
        for (int zz = 0; zz < E_NUM; zz++)
            if (xx >= xo[zz] && xx < xo[zz + 1]) { z = zz; xl = xx - xo[zz]; }
    }
    const int rows = sh ? N_TOK : cz[z];
    const int r0 = xl * 256;
    const int c0 = y * 128;

    __shared__ __align__(16) unsigned short lds[3 * 12288];   // 72 KiB, 3-buffer ring

    const int t = threadIdx.x;
    const int lane = t & 63;
    const int wv = t >> 6;
    const int wm = wv >> 1;               // 0..3 -> 64-row band
    const int wn = wv & 1;                // 0..1 -> 64-col band

    const int widx = sh ? (PHASE == 0 ? 0 : 1) : (PHASE == 0 ? 2 + z : 10 + z);
    const unsigned short* Bmat = WtAll + (size_t)widx * C_DIM * C_DIM;
    const int* bk = buckets + z * N_TOK;

    // staging geometry: A instr j (j=0,1): rows j*128 + wv*16 + (lane>>2); B: rows wv*16+(lane>>2)
    // global source col pre-swizzled: (lane&3) ^ ((lane>>3)&3)
    const int scol = (((lane & 3) ^ ((lane >> 3) & 3)) * 8);
    const int rA0 = wv * 16 + (lane >> 2);
    const int rA1 = 128 + rA0;
    int g0, g1;
    const unsigned short* Asrc;
    if (sh) {
        Asrc = Adir;
        g0 = r0 + rA0; g1 = r0 + rA1;
    } else {
        Asrc = Agat;
        int p0 = r0 + rA0, p1 = r0 + rA1;
        int e0v = bk[p0 < rows ? p0 : rows - 1];
        int e1v = bk[p1 < rows ? p1 : rows - 1];
        g0 = (PHASE == 0) ? (e0v >> 1) : e0v;
        g1 = (PHASE == 0) ? (e1v >> 1) : e1v;
    }
    const unsigned short* ap0 = Asrc + (size_t)g0 * C_DIM + scol;
    const unsigned short* ap1 = Asrc + (size_t)g1 * C_DIM + scol;
    const unsigned short* bp  = Bmat + (size_t)(c0 + rA0) * C_DIM + scol;

    f32x4 acc[4][4];
    #pragma unroll
    for (int i = 0; i < 4; i++)
        #pragma unroll
        for (int j = 0; j < 4; j++) acc[i][j] = (f32x4){0.f, 0.f, 0.f, 0.f};

    // fragment-read swizzled k-slot: slot = fq ^ ((fr>>1)&3)
    const int fr = lane & 15;
    const int fq = lane >> 4;
    const int ks = ((fq ^ ((fr >> 1) & 3)) * 8);

    // prologue: stage tiles 0,1 into buffers 0,1 (6 vm-ops per thread outstanding)
    #pragma unroll
    for (int p = 0; p < 2; ++p) {
        unsigned short* d = lds + p * 12288;
        const int ko = p * 32;
        GLOAD_LDS(ap0 + ko, d + wv * 512 + lane * 8);
        GLOAD_LDS(ap1 + ko, d + 4096 + wv * 512 + lane * 8);
        GLOAD_LDS(bp + ko,  d + 8192 + wv * 512 + lane * 8);
    }

    #pragma unroll
    for (int kt = 0; kt < NTK; ++kt) {
        if (kt + 1 < NTK) { WAITVM(3); }   // tile kt landed; tiles kt+1/kt+2 stay in flight
        else              { WAITVM(0); }
        BAR();          // tile kt visible; all waves done reading buf[(kt+2)%3]'s old tile
        SCHEDB();
        if (kt + 2 < NTK) {
            unsigned short* d = lds + ((kt + 2) % 3) * 12288;
            const int ko = (kt + 2) * 32;
            GLOAD_LDS(ap0 + ko, d + wv * 512 + lane * 8);
            GLOAD_LDS(ap1 + ko, d + 4096 + wv * 512 + lane * 8);
            GLOAD_LDS(bp + ko,  d + 8192 + wv * 512 + lane * 8);
        }
        SCHEDB();       // stage issued before compute; compute may not hoist above
        const unsigned short* buf = lds + (kt % 3) * 12288;
        short8 afr[4], bfr[4];
        #pragma unroll
        for (int i = 0; i < 4; i++)
            afr[i] = *reinterpret_cast<const short8*>(buf + (size_t)(wm * 64 + i * 16 + fr) * 32 + ks);
        #pragma unroll
        for (int j = 0; j < 4; j++)
            bfr[j] = *reinterpret_cast<const short8*>(buf + 8192 + (size_t)(wn * 64 + j * 16 + fr) * 32 + ks);
        __builtin_amdgcn_s_setprio(1);
        #pragma unroll
        for (int i = 0; i < 4; i++)
            #pragma unroll
            for (int j = 0; j < 4; j++)
                acc[i][j] = __builtin_amdgcn_mfma_f32_16x16x32_bf16(
                    __builtin_bit_cast(bf16x8, afr[i]), __builtin_bit_cast(bf16x8, bfr[j]), acc[i][j], 0, 0, 0);
        __builtin_amdgcn_s_setprio(0);
        // single barrier per step: stage(kt+2) targets buf[(kt-1)%3], whose readers all
        // passed this step's BAR before the overwrite begins.
    }

    // ---- epilogue: rows r0 + wm*64 + i*16 + fq*4 + rr; cols c0 + wn*64 + j*16 + fr ----
    const int orow = r0 + wm * 64;
    const int ocol = c0 + wn * 64;
    if (sh) {
        #pragma unroll
        for (int i = 0; i < 4; i++)
            #pragma unroll
            for (int rr = 0; rr < 4; rr++) {
                size_t base = (size_t)(orow + i * 16 + fq * 4 + rr) * C_DIM;
                #pragma unroll
                for (int j = 0; j < 4; j++) {
                    float v = acc[i][j][rr];
                    if (PHASE == 0) { float rl = v > 0.f ? v : 0.f; v = rl * rl; }
                    dstDir[base + ocol + j * 16 + fr] = f2bf(v);
                }
            }
    } else {
        #pragma unroll
        for (int i = 0; i < 4; i++)
            #pragma unroll
            for (int rr = 0; rr < 4; rr++) {
                int pos = orow + i * 16 + fq * 4 + rr;
                if (pos < rows) {
                    int ent = bk[pos];
                    size_t base = (size_t)ent * C_DIM;
                    #pragma unroll
                    for (int j = 0; j < 4; j++) {
                        float v = acc[i][j][rr];
                        if (PHASE == 0) { float rl = v > 0.f ? v : 0.f; v = rl * rl; }
                        dstGat[base + ocol + j * 16 + fr] = f2bf(v);
                    }
                }
            }
    }
}

// ------- combine (write-only): out = S[n] + w0*Y[n,0] + w1*Y[n,1], grid-stride 512 thr -------
__global__ __launch_bounds__(512) void combine_kernel(float* __restrict__ out,
                                                      const unsigned short* __restrict__ S,
                                                      const unsigned short* __restrict__ Y,
                                                      const float* __restrict__ tw) {
    const int per_row = C_DIM / 4;
    const int total = N_TOK * per_row;
    for (int idx = blockIdx.x * blockDim.x + threadIdx.x; idx < total; idx += gridDim.x * blockDim.x) {
        int n = idx / per_row;
        int c = (idx % per_row) * 4;
        float w0 = tw[n * 2], w1 = tw[n * 2 + 1];
        const ushort4 s = *reinterpret_cast<const ushort4*>(S + (size_t)n * C_DIM + c);
        const ushort4 a = *reinterpret_cast<const ushort4*>(Y + (size_t)(n * 2) * C_DIM + c);
        const ushort4 b = *reinterpret_cast<const ushort4*>(Y + (size_t)(n * 2 + 1) * C_DIM + c);
        float4 o;
        o.x = bf2f(s.x) + w0 * bf2f(a.x) + w1 * bf2f(b.x);
        o.y = bf2f(s.y) + w0 * bf2f(a.y) + w1 * bf2f(b.y);
        o.z = bf2f(s.z) + w0 * bf2f(a.z) + w1 * bf2f(b.z);
        o.w = bf2f(s.w) + w0 * bf2f(a.w) + w1 * bf2f(b.w);
        *reinterpret_cast<float4*>(out + (size_t)n * C_DIM + c) = o;
    }
}

extern "C" void kernel_launch(void* const* d_in, const int* in_sizes, int n_in,
                              void* d_out, int out_size, void* d_ws, size_t ws_size,
                              hipStream_t stream) {
    const float* x   = (const float*)d_in[0];
    const float* wfc = (const float*)d_in[1];
    const float* wpj = (const float*)d_in[2];
    const float* w1  = (const float*)d_in[3];
    const float* w2  = (const float*)d_in[4];
    const float* rw  = (const float*)d_in[5];
    const float* bias= (const float*)d_in[6];
    float* out = (float*)d_out;

    char* ws = (char*)d_ws;
    size_t off = 0;
    auto alloc = [&](size_t bytes) { void* p = ws + off; off += (bytes + 255) & ~(size_t)255; return p; };
    unsigned short* xb   = (unsigned short*)alloc((size_t)N_TOK * C_DIM * 2);
    unsigned short* Wt   = (unsigned short*)alloc((size_t)18 * C_DIM * C_DIM * 2);
    unsigned short* H    = (unsigned short*)alloc((size_t)N_TOK * 2 * C_DIM * 2);  // expert hidden, by entry
    unsigned short* Hsh  = (unsigned short*)alloc((size_t)N_TOK * C_DIM * 2);      // shared hidden
    unsigned short* S    = (unsigned short*)alloc((size_t)N_TOK * C_DIM * 2);      // shared out (bf16)
    unsigned short* Y    = (unsigned short*)alloc((size_t)N_TOK * 2 * C_DIM * 2);  // expert out, by entry
    float* topk_w        = (float*)alloc((size_t)N_TOK * 2 * 4);
    int* counts          = (int*)alloc(256);
    int* buckets         = (int*)alloc((size_t)E_NUM * N_TOK * 4);
    int* eids            = (int*)alloc((size_t)2 * N_TOK * 4);

    prep_kernel<<<PREP_TOT, 256, 0, stream>>>(wfc, wpj, w1, w2, Wt, x, rw, bias, topk_w, eids, xb);
    bucketize_kernel<<<E_NUM, 1024, 0, stream>>>(eids, counts, buckets);

    gemm_all_kernel<0><<<GRIDG, 512, 0, stream>>>(xb, xb, Wt, Hsh, H, counts, buckets);
    gemm_all_kernel<1><<<GRIDG, 512, 0, stream>>>(Hsh, H, Wt, S, Y, counts, buckets);

    combine_kernel<<<2048, 512, 0, stream>>>(out, S, Y, topk_w);
}